// Round 12
// baseline (154.576 us; speedup 1.0000x reference)
//
#include <hip/hip_runtime.h>

// SAGPool on MI355X, round 12: register-resident T via v_readlane.
// Single launch, 128 blocks x 1024 threads (no cooperative launch: R11's
// coop kernel killed the container twice under graph capture).
// Evidence chain: R8/R10 show the wall is per-CU LDS wave-instructions,
// dominated by phase-2 T broadcasts (scale with wave count). Fix: wave w's
// lane r computes T[r, c0..c0+7] in registers (phase 1, W scalar-loaded);
// phase 2 gets T[j, c0..c0+7] from lane j of the SAME wave via
// __builtin_amdgcn_readlane (VALU/SGPR path, zero LDS). T never touches LDS.
// LDS traffic left: X row reads, A row reads, H writes - all conflict-free.

#define NGRAPH 128
#define EPG    1024
#define ETOT   131072
#define DIM    128
#define KSEL   32
#define SA     68       // A row stride
#define SF     132      // X/H row stride

// LDS layout (floats)
#define O_A    0                     // 64*68  = 4352
#define O_B0   4352                  // 64*132 = 8448 (feature ping)
#define O_B1   12800                 // 64*132 = 8448 (feature pong)
#define O_PPAR 21248                 // 16*64  = 1024
#define O_PRE  22272                 // 64
#define O_SC   22336                 // 64
#define O_SEL  22400                 // 64
#define LDS_FLOATS 22464
#define LDS_BYTES  (LDS_FLOATS * 4)  // 89856
// tail scratch aliases B0 (dead after layer 3, which reads B0 as input):
#define O_RO   O_B0                  // 768
#define O_MH   (O_B0 + 768)          // 1024
#define O_HM   (O_B0 + 1792)         // 128
#define O_H2M  (O_B0 + 1920)         // 64

#define FMA8(A, xs, w0, w1) do { \
  A[0] += (xs)*(w0).x; A[1] += (xs)*(w0).y; A[2] += (xs)*(w0).z; A[3] += (xs)*(w0).w; \
  A[4] += (xs)*(w1).x; A[5] += (xs)*(w1).y; A[6] += (xs)*(w1).z; A[7] += (xs)*(w1).w; } while(0)

__device__ __forceinline__ float rdlane(float v, int lane) {
  return __int_as_float(__builtin_amdgcn_readlane(__float_as_int(v), lane));
}

// One GCN layer. lane r = tid&63 (row), wave w = tid>>6 (col-oct, uniform).
// phase 1: acc[8] = T[r, c0..c0+7] = Bin[r,:] @ W[:,c0..7]  (W scalar loads)
// phase 2: H[r, c0..7] = relu(sum_j A[r,j] * readlane(acc, j) + b)
// -> Bout (LDS) + Hg (global); pre[r] += H[r,:].waCol via ppar.
__device__ void gcn_layer(float* lds, const float* Bin, float* Bout,
                          const float* __restrict__ Wg,
                          const float* __restrict__ bg,
                          const float* __restrict__ waCol,
                          float* __restrict__ Hg, int tid)
{
  float* sA   = lds + O_A;
  float* ppar = lds + O_PPAR;
  float* pre  = lds + O_PRE;
  const int r  = tid & 63;
  const int w  = tid >> 6;
  const int c0 = __builtin_amdgcn_readfirstlane(w * 8);   // uniform -> s_load

  // ---- phase 1: T in registers ----
  float acc[8] = {0.f,0.f,0.f,0.f,0.f,0.f,0.f,0.f};
  const float* wp = Wg + c0;
  #pragma unroll 2
  for (int kq = 0; kq < 32; ++kq) {
    float4 xv = *(const float4*)&Bin[r * SF + kq * 4];    // per-row LDS read
    const float* wr = wp + (kq * 4) * DIM;                // uniform -> SGPRs
    float4 w00 = *(const float4*)&wr[0];
    float4 w01 = *(const float4*)&wr[4];
    float4 w10 = *(const float4*)&wr[DIM];
    float4 w11 = *(const float4*)&wr[DIM + 4];
    float4 w20 = *(const float4*)&wr[2 * DIM];
    float4 w21 = *(const float4*)&wr[2 * DIM + 4];
    float4 w30 = *(const float4*)&wr[3 * DIM];
    float4 w31 = *(const float4*)&wr[3 * DIM + 4];
    FMA8(acc, xv.x, w00, w01);
    FMA8(acc, xv.y, w10, w11);
    FMA8(acc, xv.z, w20, w21);
    FMA8(acc, xv.w, w30, w31);
  }
  // no sync: phase 2 consumes acc within the same wave.

  // ---- phase 2: H = relu(A @ T + b), T via readlane ----
  float4 bv0 = *(const float4*)&bg[c0];                   // uniform -> scalar
  float4 bv1 = *(const float4*)&bg[c0 + 4];
  float h[8];
  h[0] = bv0.x; h[1] = bv0.y; h[2] = bv0.z; h[3] = bv0.w;
  h[4] = bv1.x; h[5] = bv1.y; h[6] = bv1.z; h[7] = bv1.w;
  for (int jq = 0; jq < 16; ++jq) {
    float4 a4 = *(const float4*)&sA[r * SA + jq * 4];     // per-row LDS read
    #pragma unroll
    for (int jj = 0; jj < 4; ++jj) {
      const int lane = jq * 4 + jj;                       // uniform -> SGPR idx
      const float aj = (jj == 0) ? a4.x : (jj == 1) ? a4.y
                     : (jj == 2) ? a4.z : a4.w;
      #pragma unroll
      for (int c = 0; c < 8; ++c)
        h[c] += aj * rdlane(acc[c], lane);
    }
  }
  float4 o0, o1;
  o0.x = fmaxf(h[0], 0.f); o0.y = fmaxf(h[1], 0.f);
  o0.z = fmaxf(h[2], 0.f); o0.w = fmaxf(h[3], 0.f);
  o1.x = fmaxf(h[4], 0.f); o1.y = fmaxf(h[5], 0.f);
  o1.z = fmaxf(h[6], 0.f); o1.w = fmaxf(h[7], 0.f);
  *(float4*)&Bout[r * SF + c0]     = o0;                  // ping-pong, no race
  *(float4*)&Bout[r * SF + c0 + 4] = o1;
  *(float4*)&Hg[r * DIM + c0]      = o0;                  // for tail readout
  *(float4*)&Hg[r * DIM + c0 + 4]  = o1;
  float4 wa0 = *(const float4*)&waCol[c0];
  float4 wa1 = *(const float4*)&waCol[c0 + 4];
  ppar[w * 64 + r] = o0.x*wa0.x + o0.y*wa0.y + o0.z*wa0.z + o0.w*wa0.w
                   + o1.x*wa1.x + o1.y*wa1.y + o1.z*wa1.z + o1.w*wa1.w;
  __syncthreads();                 // Bout + ppar complete
  if (tid < 64) {
    float s = 0.f;
    #pragma unroll
    for (int q = 0; q < 16; ++q) s += ppar[q * 64 + tid];
    pre[tid] += s;
  }
  __syncthreads();                 // pre done; ppar free for next layer
}

extern "C" __global__ void __launch_bounds__(1024)
sagpool(const float* __restrict__ x,  const int* __restrict__ ei,
        const float* __restrict__ W1, const float* __restrict__ b1,
        const float* __restrict__ W2, const float* __restrict__ b2,
        const float* __restrict__ W3, const float* __restrict__ b3,
        const float* __restrict__ Wa, const float* __restrict__ ba,
        const float* __restrict__ M1, const float* __restrict__ c1,
        const float* __restrict__ M2, const float* __restrict__ c2,
        const float* __restrict__ M3, const float* __restrict__ c3,
        float* __restrict__ h1w, float* __restrict__ h2w,
        float* __restrict__ h3w, float* __restrict__ out)
{
  extern __shared__ float lds[];
  const int g = blockIdx.x, tid = threadIdx.x;
  float* sA  = lds + O_A;
  float* B0  = lds + O_B0;
  float* B1  = lds + O_B1;
  float* pre = lds + O_PRE;
  float* sc  = lds + O_SC;   // dinv, later score
  float* sel = lds + O_SEL;
  float* ro  = lds + O_RO;
  float* mh  = lds + O_MH;
  float* hm  = lds + O_HM;
  float* h2m = lds + O_H2M;

  // ---- adjacency: build, +I, D^-1/2 normalize ----
  for (int i = tid; i < 64 * SA; i += 1024) sA[i] = 0.f;
  if (tid < 64) pre[tid] = 0.f;
  __syncthreads();
  {
    int s = ei[g * EPG + tid] & 63;           // EPG == blockDim.x
    int d = ei[ETOT + g * EPG + tid] & 63;
    sA[s * SA + d] = 1.0f;
    sA[d * SA + s] = 1.0f;
  }
  __syncthreads();
  if (tid < 64) sA[tid * SA + tid] += 1.0f;   // +I (self-edge -> 2, matches ref)
  __syncthreads();
  {
    int r = tid >> 4, q = tid & 15;
    float sum = sA[r * SA + q * 4]     + sA[r * SA + q * 4 + 1]
              + sA[r * SA + q * 4 + 2] + sA[r * SA + q * 4 + 3];
    sum += __shfl_xor(sum, 1);
    sum += __shfl_xor(sum, 2);
    sum += __shfl_xor(sum, 4);
    sum += __shfl_xor(sum, 8);
    if (q == 0) sc[r] = 1.0f / sqrtf(sum);
  }
  __syncthreads();
  for (int i = tid; i < 4096; i += 1024) {
    int r = i >> 6, c = i & 63;
    sA[r * SA + c] *= sc[r] * sc[c];
  }
  { // stage x into B0 [64][132]
    const float4* xg = (const float4*)(x + g * 64 * DIM);
    for (int i = tid; i < 2048; i += 1024) {
      int r = i >> 5, q = i & 31;
      *(float4*)&B0[r * SF + q * 4] = xg[i];
    }
  }
  __syncthreads();

  // ---- 3 GCN layers (B0 -> B1 -> B0 -> B1) ----
  gcn_layer(lds, B0, B1, W1, b1, Wa,           h1w + g * 8192, tid);
  gcn_layer(lds, B1, B0, W2, b2, Wa + DIM,     h2w + g * 8192, tid);
  gcn_layer(lds, B0, B1, W3, b3, Wa + 2 * DIM, h3w + g * 8192, tid);

  // ---- score = tanh(A @ pre + ba) ----
  {
    int r = tid >> 4, q = tid & 15;
    float p = sA[r * SA + q * 4]     * pre[q * 4]
            + sA[r * SA + q * 4 + 1] * pre[q * 4 + 1]
            + sA[r * SA + q * 4 + 2] * pre[q * 4 + 2]
            + sA[r * SA + q * 4 + 3] * pre[q * 4 + 3];
    p += __shfl_xor(p, 1);
    p += __shfl_xor(p, 2);
    p += __shfl_xor(p, 4);
    p += __shfl_xor(p, 8);
    if (q == 0) sc[r] = tanhf(p + ba[0]);
  }
  __syncthreads();

  // ---- top-K by rank (value desc, index asc = lax.top_k tie order) ----
  if (tid < 64) {
    float mys = sc[tid];
    int cnt = 0;
    for (int j = 0; j < 64; ++j) {
      float sj = sc[j];
      cnt += (sj > mys || (sj == mys && j < tid)) ? 1 : 0;
    }
    sel[tid] = (cnt < KSEL) ? 1.0f : 0.0f;
  }
  __syncthreads();

  // ---- readout: mean || max of score-scaled selected rows (H from global) ----
  if (tid < 768) {
    int c = tid >> 1, half = tid & 1;          // c in 0..383
    int which = c >> 7, cc = c & 127;
    const float* hb = ((which == 0) ? h1w : (which == 1) ? h2w : h3w) + g * 8192;
    float sum = 0.f, mx = -1e30f;
    for (int i = half * 32; i < half * 32 + 32; ++i) {
      if (sel[i] > 0.5f) {
        float v = sc[i] * hb[i * DIM + cc];
        sum += v;
        mx = fmaxf(mx, v);
      }
    }
    sum += __shfl_xor(sum, 1);
    mx = fmaxf(mx, __shfl_xor(mx, 1));
    if (half == 0) {
      ro[c]       = sum * (1.0f / KSEL);
      ro[384 + c] = mx;
    }
  }
  __syncthreads();

  // ---- MLP: 768 -> 128 -> 64 -> 10 ----
  {
    int j = tid & 127, oc = tid >> 7;          // 8 k-chunks of 96
    float a = 0.f;
    int k0 = oc * 96;
    for (int k = k0; k < k0 + 96; k += 4) {
      float4 r4 = *(const float4*)&ro[k];
      a += r4.x * M1[(k + 0) * DIM + j];
      a += r4.y * M1[(k + 1) * DIM + j];
      a += r4.z * M1[(k + 2) * DIM + j];
      a += r4.w * M1[(k + 3) * DIM + j];
    }
    mh[oc * 128 + j] = a;
  }
  __syncthreads();
  if (tid < 128) {
    float v = c1[tid];
    #pragma unroll
    for (int q = 0; q < 8; ++q) v += mh[q * 128 + tid];
    hm[tid] = fmaxf(v, 0.f);
  }
  __syncthreads();
  if (tid < 64) {
    float a = c2[tid];
    for (int k = 0; k < 128; ++k) a += hm[k] * M2[k * 64 + tid];
    h2m[tid] = fmaxf(a, 0.f);
  }
  __syncthreads();
  if (tid < 10) {
    float a = c3[tid];
    for (int k = 0; k < 64; ++k) a += h2m[k] * M3[k * 10 + tid];
    out[g * 10 + tid] = a;
  }
}

extern "C" void kernel_launch(void* const* d_in, const int* in_sizes, int n_in,
                              void* d_out, int out_size, void* d_ws, size_t ws_size,
                              hipStream_t stream) {
  const float* x  = (const float*)d_in[0];
  const int*   ei = (const int*)d_in[1];
  // d_in[2] (batch) unused: graphs are contiguous 64-node blocks
  const float* W1 = (const float*)d_in[3];
  const float* b1 = (const float*)d_in[4];
  const float* W2 = (const float*)d_in[5];
  const float* b2 = (const float*)d_in[6];
  const float* W3 = (const float*)d_in[7];
  const float* b3 = (const float*)d_in[8];
  const float* Wa = (const float*)d_in[9];
  const float* ba = (const float*)d_in[10];
  const float* M1 = (const float*)d_in[11];
  const float* c1 = (const float*)d_in[12];
  const float* M2 = (const float*)d_in[13];
  const float* c2 = (const float*)d_in[14];
  const float* M3 = (const float*)d_in[15];
  const float* c3 = (const float*)d_in[16];
  float* out = (float*)d_out;

  float* ws  = (float*)d_ws;
  float* h1w = ws;                    // 128*64*128 = 1M floats each
  float* h2w = ws + 1048576;
  float* h3w = ws + 2097152;

  (void)hipFuncSetAttribute(reinterpret_cast<const void*>(sagpool),
                            hipFuncAttributeMaxDynamicSharedMemorySize, LDS_BYTES);
  sagpool<<<NGRAPH, 1024, LDS_BYTES, stream>>>(x, ei, W1, b1, W2, b2, W3, b3,
                                               Wa, ba, M1, c1, M2, c2, M3, c3,
                                               h1w, h2w, h3w, out);
}